// Round 15
// baseline (57.855 us; speedup 1.0000x reference)
//
#include <hip/hip_runtime.h>

// Encoding layer, fused, MFMA version. B=32, C=256, K=32, N=4096.
// R15 = R14 chunk structure, grid 1024 blocks x 128 tokens x NCH=4 (3 blocks/CU by LDS).
// ws (partial path, floats): wxpT[1024*8192] @0 | wsum[1024] @8388608 | abp4[128] @8389632 | cwh @8389760
// ws (fallback,    floats): wx[262144] @0 | wsum[1024] @262144 | abp4[128] @263168 | cwh @263296

#define CC 256
#define KK 32
#define NN 4096
#define CN (CC*NN)
#define TOK 128
#define CHK 32
#define NCH 4

typedef unsigned int u32;
typedef unsigned short u16;
typedef __fp16 half2_t __attribute__((ext_vector_type(2)));
typedef _Float16 f16x8 __attribute__((ext_vector_type(8)));
typedef float f32x4 __attribute__((ext_vector_type(4)));
typedef u32 u32x2 __attribute__((ext_vector_type(2)));

__device__ __forceinline__ u32 pack2(float a, float b) {
    half2_t h = __builtin_amdgcn_cvt_pkrtz(a, b);
    u32 u;
    __builtin_memcpy(&u, &h, 4);
    return u;
}

__device__ __forceinline__ void bar_lgkm() {
    asm volatile("s_waitcnt lgkmcnt(0)" ::: "memory");
    __builtin_amdgcn_s_barrier();
    __builtin_amdgcn_sched_barrier(0);
}

#define STAGE_LOAD(CT) {                                                     \
    const float* xp = x + (size_t)b * CN + n0 + (CT) * CHK + (l & 7) * 4;    \
    _Pragma("unroll")                                                        \
    for (int it = 0; it < 8; ++it) {                                         \
        int ch = it * 32 + w * 8 + (l >> 3);                                 \
        sf[it] = *(const float4*)(xp + (size_t)ch * NN);                     \
    }                                                                        \
}
#define STAGE_WRITE(XTB, SQB) {                                              \
    float s0 = 0.f, s1 = 0.f, s2 = 0.f, s3 = 0.f;                            \
    int tq = l & 7;                                                          \
    _Pragma("unroll")                                                        \
    for (int it = 0; it < 8; ++it) {                                         \
        int ch = it * 32 + w * 8 + (l >> 3);                                 \
        float4 f = sf[it];                                                   \
        s0 += f.x * f.x; s1 += f.y * f.y;                                    \
        s2 += f.z * f.z; s3 += f.w * f.w;                                    \
        u32 u0 = pack2(f.x, f.y), u1 = pack2(f.z, f.w);                      \
        *(uint2*)(&(XTB)[((ch >> 2) * 2 + (tq >> 2)) * 64 +                  \
                         (ch & 3) * 16 + (tq & 3) * 4]) =                    \
            make_uint2(u0, u1);                                              \
    }                                                                        \
    s0 += __shfl_xor(s0, 8); s0 += __shfl_xor(s0, 16); s0 += __shfl_xor(s0, 32); \
    s1 += __shfl_xor(s1, 8); s1 += __shfl_xor(s1, 16); s1 += __shfl_xor(s1, 32); \
    s2 += __shfl_xor(s2, 8); s2 += __shfl_xor(s2, 16); s2 += __shfl_xor(s2, 32); \
    s3 += __shfl_xor(s3, 8); s3 += __shfl_xor(s3, 16); s3 += __shfl_xor(s3, 32); \
    if (l < 8) *(float4*)&(SQB)[w * 32 + tq * 4] = make_float4(s0, s1, s2, s3);  \
}

// ---------------- prep: abp table + fp16 codewords [k][ch] ----------------
__global__ void enc_prep(const float* __restrict__ cw, const float* __restrict__ scale,
                         float* __restrict__ abp4, u16* __restrict__ cwh) {
    int tid = threadIdx.x;
    {
        int k = tid >> 3, p = tid & 7;
        float s = 0.f;
        #pragma unroll
        for (int i = 0; i < 32; ++i) {
            float v = cw[k * 256 + p * 32 + i];
            s += v * v;
        }
        s += __shfl_xor(s, 1);
        s += __shfl_xor(s, 2);
        s += __shfl_xor(s, 4);
        if (p == 0) {
            float A = scale[k];
            abp4[k * 4 + 0] = A;
            abp4[k * 4 + 1] = A * s;
            abp4[k * 4 + 2] = -2.f * A;
            abp4[k * 4 + 3] = 0.f;
        }
    }
    for (int i = 0; i < 32; ++i) {
        int idx = i * 256 + tid;
        union { __fp16 h; u16 u; } cv;
        cv.h = (__fp16)cw[idx];
        cwh[idx] = cv.u;
    }
}

#define PA_ISSUE(KS, P, A0, A1) {                                                \
    asm volatile("ds_read_b64_tr_b16 %0, %1 offset:%2"                           \
                 : "=v"(trA[P][0]) : "v"(A0), "i"((KS) * 2048));                 \
    asm volatile("ds_read_b64_tr_b16 %0, %1 offset:%2"                           \
                 : "=v"(trA[P][1]) : "v"(A0), "i"((KS) * 2048 + 256));           \
    asm volatile("ds_read_b64_tr_b16 %0, %1 offset:%2"                           \
                 : "=v"(trA[P][2]) : "v"(A1), "i"((KS) * 2048));                 \
    asm volatile("ds_read_b64_tr_b16 %0, %1 offset:%2"                           \
                 : "=v"(trA[P][3]) : "v"(A1), "i"((KS) * 2048 + 256));           \
}

// ---------------- fused main: 1024 blocks x 256 threads, 128 tokens each ----------------
__global__ __launch_bounds__(256, 2) void enc_main(
    const float* __restrict__ x, const u16* __restrict__ cwh,
    const float* __restrict__ abp4, float* __restrict__ wxp, float* __restrict__ wsum,
    int use_partials) {

    __shared__ u16   xt[2][8192];     // 2 x 16 KB, double buffer (chunk parity)
    __shared__ u16   w2sp[4][1024];   // per-wave-private P [k][t]
    __shared__ float swsq[2][128];    // xsq partials, double buffer

    const int tid = threadIdx.x;
    const int l   = tid & 63;
    const int w   = tid >> 6;
    const int b   = blockIdx.x >> 5;
    const int blk = blockIdx.x & 31;
    const int n0  = blk * TOK;
    const int lg  = (l >> 4) & 3;

    // cw A-frags, preloaded ONCE: cwA[ks][Mt] (64 VGPRs), L2-warm source
    uint4 cwA[8][2];
    {
        const u32* cwg = (const u32*)cwh + (l & 15) * 128 + lg * 4;
        #pragma unroll
        for (int ks = 0; ks < 8; ++ks) {
            cwA[ks][0] = *(const uint4*)(cwg + ks * 16);
            cwA[ks][1] = *(const uint4*)(cwg + 2048 + ks * 16);
        }
    }
    // softmax per-k constants: lane's k = Mt*16 + lg*4 + r
    float Ak[2][4], Bk[2][4], Pk[2][4];
    #pragma unroll
    for (int Mt = 0; Mt < 2; ++Mt)
        #pragma unroll
        for (int r = 0; r < 4; ++r) {
            const float* ap = abp4 + (Mt * 16 + lg * 4 + r) * 4;
            Ak[Mt][r] = ap[0]; Bk[Mt][r] = ap[1]; Pk[Mt][r] = ap[2];
        }

    f32x4 accb[4][2];   // [ch-tile q][k-tile nk]
    #pragma unroll
    for (int q = 0; q < 4; ++q)
        #pragma unroll
        for (int nk = 0; nk < 2; ++nk)
            accb[q][nk] = (f32x4){0.f, 0.f, 0.f, 0.f};
    float wsacc[2][4];
    #pragma unroll
    for (int Mt = 0; Mt < 2; ++Mt)
        #pragma unroll
        for (int r = 0; r < 4; ++r) wsacc[Mt][r] = 0.f;

    float4 sf[8];

    STAGE_LOAD(0);

    for (int ct = 0; ct < NCH; ++ct) {
        const int p2 = ct & 1;
        u16* xtb = &xt[p2][0];
        float* sqb = &swsq[p2][0];

        STAGE_WRITE(xtb, sqb);
        bar_lgkm();               // the ONLY barrier per chunk

        const u32 a0 = (u32)(uintptr_t)xtb + (4 * (l >> 4)) * 128 + (l & 15) * 8;
        const u32 a1 = a0 + 128;

        // ---- pass A: S[k][t] = Cw·X^T (cw frags in regs, tr_reads 1-deep) ----
        f32x4 acca[2][2];
        #pragma unroll
        for (int Mt = 0; Mt < 2; ++Mt)
            #pragma unroll
            for (int Nt = 0; Nt < 2; ++Nt)
                acca[Mt][Nt] = (f32x4){0.f, 0.f, 0.f, 0.f};
        {
            u32x2 trA[2][4];
            PA_ISSUE(0, 0, a0, a1);
            #pragma unroll
            for (int ks = 0; ks < 8; ++ks) {
                const int p = ks & 1;
                if (ks < 7) {
                    if (p == 0) { PA_ISSUE(ks + 1, 1, a0, a1); }
                    else        { PA_ISSUE(ks + 1, 0, a0, a1); }
                    asm volatile("s_waitcnt lgkmcnt(4)");
                } else {
                    asm volatile("s_waitcnt lgkmcnt(0)");
                }
                __builtin_amdgcn_sched_barrier(0);
                #pragma unroll
                for (int Nt = 0; Nt < 2; ++Nt) {
                    union { uint4 u; f16x8 h; } af;
                    af.u = make_uint4(trA[p][2 * Nt].x, trA[p][2 * Nt].y,
                                      trA[p][2 * Nt + 1].x, trA[p][2 * Nt + 1].y);
                    #pragma unroll
                    for (int Mt = 0; Mt < 2; ++Mt) {
                        union { uint4 u; f16x8 h; } cf;
                        cf.u = cwA[ks][Mt];
                        acca[Mt][Nt] = __builtin_amdgcn_mfma_f32_16x16x32_f16(
                            cf.h, af.h, acca[Mt][Nt], 0, 0, 0);
                    }
                }
            }
        }

        // ---- issue next-chunk global loads (no barrier crossing until next STAGE_WRITE) ----
        if (ct < NCH - 1) STAGE_LOAD(ct + 1);

        // ---- in-register softmax (token t = Nt*16 + (l&15)) ----
        {
            #pragma unroll
            for (int Nt = 0; Nt < 2; ++Nt) {
                int t = Nt * 16 + (l & 15);
                float xq = sqb[t] + sqb[32 + t] + sqb[64 + t] + sqb[96 + t];
                float lgt[2][4];
                float m = -3.4e38f;
                #pragma unroll
                for (int Mt = 0; Mt < 2; ++Mt)
                    #pragma unroll
                    for (int r = 0; r < 4; ++r) {
                        lgt[Mt][r] = fmaf(Ak[Mt][r], xq, Bk[Mt][r]) + Pk[Mt][r] * acca[Mt][Nt][r];
                        m = fmaxf(m, lgt[Mt][r]);
                    }
                m = fmaxf(m, __shfl_xor(m, 16));
                m = fmaxf(m, __shfl_xor(m, 32));
                float s = 0.f, e[2][4];
                #pragma unroll
                for (int Mt = 0; Mt < 2; ++Mt)
                    #pragma unroll
                    for (int r = 0; r < 4; ++r) { e[Mt][r] = __expf(lgt[Mt][r] - m); s += e[Mt][r]; }
                s += __shfl_xor(s, 16);
                s += __shfl_xor(s, 32);
                float rcp = 1.0f / s;
                #pragma unroll
                for (int Mt = 0; Mt < 2; ++Mt)
                    #pragma unroll
                    for (int r = 0; r < 4; ++r) {
                        float wv = e[Mt][r] * rcp;
                        wsacc[Mt][r] += wv;
                        union { __fp16 h; u16 u; } cv;
                        cv.h = (__fp16)wv;
                        w2sp[w][(Mt * 16 + lg * 4 + r) * 32 + Nt * 16 + (l & 15)] = cv.u;
                    }
            }
        }
        // w2sp same-wave write->read ordered by compiler-inserted lgkmcnt

        // ---- pass B: wx^T[ch][k] += X^T·P^T ----
        {
            f16x8 pB[2];
            #pragma unroll
            for (int nk = 0; nk < 2; ++nk)
                pB[nk] = *(const f16x8*)&w2sp[w][(nk * 16 + (l & 15)) * 32 + lg * 8];
            #pragma unroll
            for (int q = 0; q < 4; ++q) {
                int ch = (w * 4 + q) * 16 + (l & 15);
                const f16x8 xA = *(const f16x8*)&xtb[((ch >> 2) * 2 + (l >> 5)) * 64 +
                                                     (ch & 3) * 16 + ((l >> 4) & 1) * 8];
                #pragma unroll
                for (int nk = 0; nk < 2; ++nk)
                    accb[q][nk] = __builtin_amdgcn_mfma_f32_16x16x32_f16(xA, pB[nk], accb[q][nk], 0, 0, 0);
            }
        }
        // no trailing barrier: next STAGE_WRITE targets the other buffer
    }

    // ---- epilogue: wsum (wave 0 counts each token once) ----
    #pragma unroll
    for (int Mt = 0; Mt < 2; ++Mt)
        #pragma unroll
        for (int r = 0; r < 4; ++r) {
            float v = wsacc[Mt][r];
            v += __shfl_xor(v, 1); v += __shfl_xor(v, 2);
            v += __shfl_xor(v, 4); v += __shfl_xor(v, 8);
            if (w == 0 && (l & 15) == 0)
                atomicAdd(&wsum[b * KK + Mt * 16 + lg * 4 + r], v);
        }
    // ---- wx^T partial stores: wxpT[block][ch][k] ----
    if (use_partials) {
        float* dst = wxp + (size_t)blockIdx.x * 8192;
        #pragma unroll
        for (int q = 0; q < 4; ++q)
            #pragma unroll
            for (int nk = 0; nk < 2; ++nk)
                #pragma unroll
                for (int r = 0; r < 4; ++r) {
                    int ch = (w * 4 + q) * 16 + lg * 4 + r;
                    int k  = nk * 16 + (l & 15);
                    dst[ch * 32 + k] = accb[q][nk][r];
                }
    } else {
        #pragma unroll
        for (int q = 0; q < 4; ++q)
            #pragma unroll
            for (int nk = 0; nk < 2; ++nk)
                #pragma unroll
                for (int r = 0; r < 4; ++r) {
                    int ch = (w * 4 + q) * 16 + lg * 4 + r;
                    int k  = nk * 16 + (l & 15);
                    atomicAdd(&wxp[(size_t)b * 8192 + k * 256 + ch], accb[q][nk][r]);
                }
    }
}

// ---------------- finalize (partial path): coalesced (k-fastest threads) ----------------
__global__ void enc_final_part(const float* __restrict__ wxp, const float* __restrict__ wsum,
                               const float* __restrict__ cw, float* __restrict__ out) {
    int i = blockIdx.x * 256 + threadIdx.x;
    int k = i & 31, c = (i >> 5) & 255, b = i >> 13;
    const float* p = wxp + (size_t)b * 32 * 8192 + c * 32 + k;
    float s = 0.f;
    #pragma unroll
    for (int j = 0; j < 32; ++j) s += p[(size_t)j * 8192];
    out[(size_t)b * 8192 + k * 256 + c] = s - wsum[b * 32 + k] * cw[k * 256 + c];
}
__global__ void enc_final_atomic(const float* __restrict__ wx, const float* __restrict__ wsum,
                                 const float* __restrict__ cw, float* __restrict__ out) {
    int i = blockIdx.x * 256 + threadIdx.x;
    int c = i & 255, k = (i >> 8) & 31, b = i >> 13;
    out[i] = wx[i] - wsum[b * 32 + k] * cw[k * 256 + c];
}

extern "C" void kernel_launch(void* const* d_in, const int* in_sizes, int n_in,
                              void* d_out, int out_size, void* d_ws, size_t ws_size,
                              hipStream_t stream) {
    (void)in_sizes; (void)n_in; (void)out_size;
    const float* x     = (const float*)d_in[0];
    const float* cw    = (const float*)d_in[1];
    const float* scale = (const float*)d_in[2];
    float* out = (float*)d_out;
    float* wsf = (float*)d_ws;

    const size_t need = (size_t)(8388608 + 1024 + 128 + 4096) * 4;
    const int use_partials = (ws_size >= need) ? 1 : 0;

    float *wxp, *wsum, *abp4;
    u16* cwh;
    if (use_partials) {
        wxp  = wsf;                        // 8388608 f32 (1024 block tiles, [ch][k])
        wsum = wsf + 8388608;              // 1024 f32
        abp4 = wsf + 8389632;              // 128 f32
        cwh  = (u16*)(wsf + 8389760);      // 8192 u16
        (void)hipMemsetAsync(wsum, 0, 1024 * sizeof(float), stream);
    } else {
        wxp  = wsf;                        // 262144 f32
        wsum = wsf + 262144;               // 1024 f32
        abp4 = wsf + 263168;               // 128 f32
        cwh  = (u16*)(wsf + 263296);       // 8192 u16
        (void)hipMemsetAsync(d_ws, 0, 263168 * sizeof(float), stream);
    }

    hipLaunchKernelGGL(enc_prep, dim3(1),    dim3(256), 0, stream, cw, scale, abp4, cwh);
    hipLaunchKernelGGL(enc_main, dim3(1024), dim3(256), 0, stream, x, cwh, abp4, wxp, wsum, use_partials);
    if (use_partials)
        hipLaunchKernelGGL(enc_final_part,   dim3(1024), dim3(256), 0, stream, wxp, wsum, cw, out);
    else
        hipLaunchKernelGGL(enc_final_atomic, dim3(1024), dim3(256), 0, stream, wxp, wsum, cw, out);
}

// Round 16
// 45.248 us; speedup vs baseline: 1.2786x; 1.2786x over previous
//
#include <hip/hip_runtime.h>

// Encoding layer, fused, MFMA version. B=32, C=256, K=32, N=4096.
// R16 = R14 (best: 512 blocks x 256 tok x NCH=8, 1 barrier/chunk, dbuf LDS)
//   + STAGE_LOAD issued BEFORE pass A (sched_barrier fences blocked compiler hoisting)
//   + fp16 partial tiles (33.6 -> 16.8 MB round-trip).
// ws (partial path): wxh u16[512*8192] @0 | wsum f32 @f32ofs 2097152 | abp4 @2098176 | cwh @2098304
// ws (fallback, floats): wx[262144] @0 | wsum[1024] @262144 | abp4[128] @263168 | cwh @263296

#define CC 256
#define KK 32
#define NN 4096
#define CN (CC*NN)
#define TOK 256
#define CHK 32
#define NCH 8

typedef unsigned int u32;
typedef unsigned short u16;
typedef __fp16 half2_t __attribute__((ext_vector_type(2)));
typedef _Float16 f16x8 __attribute__((ext_vector_type(8)));
typedef float f32x4 __attribute__((ext_vector_type(4)));
typedef u32 u32x2 __attribute__((ext_vector_type(2)));

__device__ __forceinline__ u32 pack2(float a, float b) {
    half2_t h = __builtin_amdgcn_cvt_pkrtz(a, b);
    u32 u;
    __builtin_memcpy(&u, &h, 4);
    return u;
}

__device__ __forceinline__ void bar_lgkm() {
    asm volatile("s_waitcnt lgkmcnt(0)" ::: "memory");
    __builtin_amdgcn_s_barrier();
    __builtin_amdgcn_sched_barrier(0);
}

#define STAGE_LOAD(CT) {                                                     \
    const float* xp = x + (size_t)b * CN + n0 + (CT) * CHK + (l & 7) * 4;    \
    _Pragma("unroll")                                                        \
    for (int it = 0; it < 8; ++it) {                                         \
        int ch = it * 32 + w * 8 + (l >> 3);                                 \
        sf[it] = *(const float4*)(xp + (size_t)ch * NN);                     \
    }                                                                        \
}
#define STAGE_WRITE(XTB, SQB) {                                              \
    float s0 = 0.f, s1 = 0.f, s2 = 0.f, s3 = 0.f;                            \
    int tq = l & 7;                                                          \
    _Pragma("unroll")                                                        \
    for (int it = 0; it < 8; ++it) {                                         \
        int ch = it * 32 + w * 8 + (l >> 3);                                 \
        float4 f = sf[it];                                                   \
        s0 += f.x * f.x; s1 += f.y * f.y;                                    \
        s2 += f.z * f.z; s3 += f.w * f.w;                                    \
        u32 u0 = pack2(f.x, f.y), u1 = pack2(f.z, f.w);                      \
        *(uint2*)(&(XTB)[((ch >> 2) * 2 + (tq >> 2)) * 64 +                  \
                         (ch & 3) * 16 + (tq & 3) * 4]) =                    \
            make_uint2(u0, u1);                                              \
    }                                                                        \
    s0 += __shfl_xor(s0, 8); s0 += __shfl_xor(s0, 16); s0 += __shfl_xor(s0, 32); \
    s1 += __shfl_xor(s1, 8); s1 += __shfl_xor(s1, 16); s1 += __shfl_xor(s1, 32); \
    s2 += __shfl_xor(s2, 8); s2 += __shfl_xor(s2, 16); s2 += __shfl_xor(s2, 32); \
    s3 += __shfl_xor(s3, 8); s3 += __shfl_xor(s3, 16); s3 += __shfl_xor(s3, 32); \
    if (l < 8) *(float4*)&(SQB)[w * 32 + tq * 4] = make_float4(s0, s1, s2, s3);  \
}

// ---------------- prep: abp table + fp16 codewords [k][ch] ----------------
__global__ void enc_prep(const float* __restrict__ cw, const float* __restrict__ scale,
                         float* __restrict__ abp4, u16* __restrict__ cwh) {
    int tid = threadIdx.x;
    {
        int k = tid >> 3, p = tid & 7;
        float s = 0.f;
        #pragma unroll
        for (int i = 0; i < 32; ++i) {
            float v = cw[k * 256 + p * 32 + i];
            s += v * v;
        }
        s += __shfl_xor(s, 1);
        s += __shfl_xor(s, 2);
        s += __shfl_xor(s, 4);
        if (p == 0) {
            float A = scale[k];
            abp4[k * 4 + 0] = A;
            abp4[k * 4 + 1] = A * s;
            abp4[k * 4 + 2] = -2.f * A;
            abp4[k * 4 + 3] = 0.f;
        }
    }
    for (int i = 0; i < 32; ++i) {
        int idx = i * 256 + tid;
        union { __fp16 h; u16 u; } cv;
        cv.h = (__fp16)cw[idx];
        cwh[idx] = cv.u;
    }
}

#define PA_ISSUE(KS, P, A0, A1) {                                                \
    asm volatile("ds_read_b64_tr_b16 %0, %1 offset:%2"                           \
                 : "=v"(trA[P][0]) : "v"(A0), "i"((KS) * 2048));                 \
    asm volatile("ds_read_b64_tr_b16 %0, %1 offset:%2"                           \
                 : "=v"(trA[P][1]) : "v"(A0), "i"((KS) * 2048 + 256));           \
    asm volatile("ds_read_b64_tr_b16 %0, %1 offset:%2"                           \
                 : "=v"(trA[P][2]) : "v"(A1), "i"((KS) * 2048));                 \
    asm volatile("ds_read_b64_tr_b16 %0, %1 offset:%2"                           \
                 : "=v"(trA[P][3]) : "v"(A1), "i"((KS) * 2048 + 256));           \
}

// ---------------- fused main: 512 blocks x 256 threads, 256 tokens each ----------------
__global__ __launch_bounds__(256, 2) void enc_main(
    const float* __restrict__ x, const u16* __restrict__ cwh,
    const float* __restrict__ abp4, u16* __restrict__ wxh, float* __restrict__ wxf,
    float* __restrict__ wsum, int use_partials) {

    __shared__ u16   xt[2][8192];     // 2 x 16 KB, double buffer (chunk parity)
    __shared__ u16   w2sp[4][1024];   // per-wave-private P [k][t]
    __shared__ float swsq[2][128];    // xsq partials, double buffer

    const int tid = threadIdx.x;
    const int l   = tid & 63;
    const int w   = tid >> 6;
    const int b   = blockIdx.x >> 4;
    const int blk = blockIdx.x & 15;
    const int n0  = blk * TOK;
    const int lg  = (l >> 4) & 3;

    // cw A-frags, preloaded ONCE: cwA[ks][Mt] (64 VGPRs), L2-warm source
    uint4 cwA[8][2];
    {
        const u32* cwg = (const u32*)cwh + (l & 15) * 128 + lg * 4;
        #pragma unroll
        for (int ks = 0; ks < 8; ++ks) {
            cwA[ks][0] = *(const uint4*)(cwg + ks * 16);
            cwA[ks][1] = *(const uint4*)(cwg + 2048 + ks * 16);
        }
    }
    // softmax per-k constants: lane's k = Mt*16 + lg*4 + r
    float Ak[2][4], Bk[2][4], Pk[2][4];
    #pragma unroll
    for (int Mt = 0; Mt < 2; ++Mt)
        #pragma unroll
        for (int r = 0; r < 4; ++r) {
            const float* ap = abp4 + (Mt * 16 + lg * 4 + r) * 4;
            Ak[Mt][r] = ap[0]; Bk[Mt][r] = ap[1]; Pk[Mt][r] = ap[2];
        }

    f32x4 accb[4][2];   // [ch-tile q][k-tile nk]
    #pragma unroll
    for (int q = 0; q < 4; ++q)
        #pragma unroll
        for (int nk = 0; nk < 2; ++nk)
            accb[q][nk] = (f32x4){0.f, 0.f, 0.f, 0.f};
    float wsacc[2][4];
    #pragma unroll
    for (int Mt = 0; Mt < 2; ++Mt)
        #pragma unroll
        for (int r = 0; r < 4; ++r) wsacc[Mt][r] = 0.f;

    float4 sf[8];

    STAGE_LOAD(0);

    for (int ct = 0; ct < NCH; ++ct) {
        const int p2 = ct & 1;
        u16* xtb = &xt[p2][0];
        float* sqb = &swsq[p2][0];

        STAGE_WRITE(xtb, sqb);
        bar_lgkm();               // the ONLY barrier per chunk

        // ---- issue next-chunk global loads EARLY: overlap pass A + softmax + pass B ----
        if (ct < NCH - 1) STAGE_LOAD(ct + 1);

        const u32 a0 = (u32)(uintptr_t)xtb + (4 * (l >> 4)) * 128 + (l & 15) * 8;
        const u32 a1 = a0 + 128;

        // ---- pass A: S[k][t] = Cw·X^T (cw frags in regs, tr_reads 1-deep) ----
        f32x4 acca[2][2];
        #pragma unroll
        for (int Mt = 0; Mt < 2; ++Mt)
            #pragma unroll
            for (int Nt = 0; Nt < 2; ++Nt)
                acca[Mt][Nt] = (f32x4){0.f, 0.f, 0.f, 0.f};
        {
            u32x2 trA[2][4];
            PA_ISSUE(0, 0, a0, a1);
            #pragma unroll
            for (int ks = 0; ks < 8; ++ks) {
                const int p = ks & 1;
                if (ks < 7) {
                    if (p == 0) { PA_ISSUE(ks + 1, 1, a0, a1); }
                    else        { PA_ISSUE(ks + 1, 0, a0, a1); }
                    asm volatile("s_waitcnt lgkmcnt(4)");
                } else {
                    asm volatile("s_waitcnt lgkmcnt(0)");
                }
                __builtin_amdgcn_sched_barrier(0);
                #pragma unroll
                for (int Nt = 0; Nt < 2; ++Nt) {
                    union { uint4 u; f16x8 h; } af;
                    af.u = make_uint4(trA[p][2 * Nt].x, trA[p][2 * Nt].y,
                                      trA[p][2 * Nt + 1].x, trA[p][2 * Nt + 1].y);
                    #pragma unroll
                    for (int Mt = 0; Mt < 2; ++Mt) {
                        union { uint4 u; f16x8 h; } cf;
                        cf.u = cwA[ks][Mt];
                        acca[Mt][Nt] = __builtin_amdgcn_mfma_f32_16x16x32_f16(
                            cf.h, af.h, acca[Mt][Nt], 0, 0, 0);
                    }
                }
            }
        }

        // ---- in-register softmax (token t = Nt*16 + (l&15)) ----
        {
            #pragma unroll
            for (int Nt = 0; Nt < 2; ++Nt) {
                int t = Nt * 16 + (l & 15);
                float xq = sqb[t] + sqb[32 + t] + sqb[64 + t] + sqb[96 + t];
                float lgt[2][4];
                float m = -3.4e38f;
                #pragma unroll
                for (int Mt = 0; Mt < 2; ++Mt)
                    #pragma unroll
                    for (int r = 0; r < 4; ++r) {
                        lgt[Mt][r] = fmaf(Ak[Mt][r], xq, Bk[Mt][r]) + Pk[Mt][r] * acca[Mt][Nt][r];
                        m = fmaxf(m, lgt[Mt][r]);
                    }
                m = fmaxf(m, __shfl_xor(m, 16));
                m = fmaxf(m, __shfl_xor(m, 32));
                float s = 0.f, e[2][4];
                #pragma unroll
                for (int Mt = 0; Mt < 2; ++Mt)
                    #pragma unroll
                    for (int r = 0; r < 4; ++r) { e[Mt][r] = __expf(lgt[Mt][r] - m); s += e[Mt][r]; }
                s += __shfl_xor(s, 16);
                s += __shfl_xor(s, 32);
                float rcp = 1.0f / s;
                #pragma unroll
                for (int Mt = 0; Mt < 2; ++Mt)
                    #pragma unroll
                    for (int r = 0; r < 4; ++r) {
                        float wv = e[Mt][r] * rcp;
                        wsacc[Mt][r] += wv;
                        union { __fp16 h; u16 u; } cv;
                        cv.h = (__fp16)wv;
                        w2sp[w][(Mt * 16 + lg * 4 + r) * 32 + Nt * 16 + (l & 15)] = cv.u;
                    }
            }
        }
        // w2sp same-wave write->read ordered by compiler-inserted lgkmcnt

        // ---- pass B: wx^T[ch][k] += X^T·P^T ----
        {
            f16x8 pB[2];
            #pragma unroll
            for (int nk = 0; nk < 2; ++nk)
                pB[nk] = *(const f16x8*)&w2sp[w][(nk * 16 + (l & 15)) * 32 + lg * 8];
            #pragma unroll
            for (int q = 0; q < 4; ++q) {
                int ch = (w * 4 + q) * 16 + (l & 15);
                const f16x8 xA = *(const f16x8*)&xtb[((ch >> 2) * 2 + (l >> 5)) * 64 +
                                                     (ch & 3) * 16 + ((l >> 4) & 1) * 8];
                #pragma unroll
                for (int nk = 0; nk < 2; ++nk)
                    accb[q][nk] = __builtin_amdgcn_mfma_f32_16x16x32_f16(xA, pB[nk], accb[q][nk], 0, 0, 0);
            }
        }
        // no trailing barrier: next STAGE_WRITE targets the other buffer
    }

    // ---- epilogue: wsum (wave 0 counts each token once) ----
    #pragma unroll
    for (int Mt = 0; Mt < 2; ++Mt)
        #pragma unroll
        for (int r = 0; r < 4; ++r) {
            float v = wsacc[Mt][r];
            v += __shfl_xor(v, 1); v += __shfl_xor(v, 2);
            v += __shfl_xor(v, 4); v += __shfl_xor(v, 8);
            if (w == 0 && (l & 15) == 0)
                atomicAdd(&wsum[b * KK + Mt * 16 + lg * 4 + r], v);
        }
    // ---- wx^T partial stores: fp16 tile [ch][k] per block ----
    if (use_partials) {
        u16* dst = wxh + (size_t)blockIdx.x * 8192;
        #pragma unroll
        for (int q = 0; q < 4; ++q)
            #pragma unroll
            for (int nk = 0; nk < 2; ++nk)
                #pragma unroll
                for (int r = 0; r < 4; ++r) {
                    int ch = (w * 4 + q) * 16 + lg * 4 + r;
                    int k  = nk * 16 + (l & 15);
                    union { __fp16 h; u16 u; } cv;
                    cv.h = (__fp16)accb[q][nk][r];
                    dst[ch * 32 + k] = cv.u;    // 16-lane 32B contiguous runs
                }
    } else {
        #pragma unroll
        for (int q = 0; q < 4; ++q)
            #pragma unroll
            for (int nk = 0; nk < 2; ++nk)
                #pragma unroll
                for (int r = 0; r < 4; ++r) {
                    int ch = (w * 4 + q) * 16 + lg * 4 + r;
                    int k  = nk * 16 + (l & 15);
                    atomicAdd(&wxf[(size_t)b * 8192 + k * 256 + ch], accb[q][nk][r]);
                }
    }
}

// ---------------- finalize (partial path): fp16 tiles, coalesced (k-fastest) ----------------
__global__ void enc_final_part(const u16* __restrict__ wxh, const float* __restrict__ wsum,
                               const float* __restrict__ cw, float* __restrict__ out) {
    int i = blockIdx.x * 256 + threadIdx.x;
    int k = i & 31, c = (i >> 5) & 255, b = i >> 13;
    const u16* p = wxh + (size_t)b * 16 * 8192 + c * 32 + k;
    float s = 0.f;
    #pragma unroll
    for (int j = 0; j < 16; ++j) {
        union { u16 u; __fp16 h; } cv;
        cv.u = p[(size_t)j * 8192];
        s += (float)cv.h;
    }
    out[(size_t)b * 8192 + k * 256 + c] = s - wsum[b * 32 + k] * cw[k * 256 + c];
}
__global__ void enc_final_atomic(const float* __restrict__ wx, const float* __restrict__ wsum,
                                 const float* __restrict__ cw, float* __restrict__ out) {
    int i = blockIdx.x * 256 + threadIdx.x;
    int c = i & 255, k = (i >> 8) & 31, b = i >> 13;
    out[i] = wx[i] - wsum[b * 32 + k] * cw[k * 256 + c];
}

extern "C" void kernel_launch(void* const* d_in, const int* in_sizes, int n_in,
                              void* d_out, int out_size, void* d_ws, size_t ws_size,
                              hipStream_t stream) {
    (void)in_sizes; (void)n_in; (void)out_size;
    const float* x     = (const float*)d_in[0];
    const float* cw    = (const float*)d_in[1];
    const float* scale = (const float*)d_in[2];
    float* out = (float*)d_out;
    float* wsf = (float*)d_ws;

    // partial path: u16[512*8192] = 2097152 f32-slots, then wsum/abp4/cwh
    const size_t need = (size_t)(2097152 + 1024 + 128 + 4096) * 4;
    const int use_partials = (ws_size >= need) ? 1 : 0;

    u16* wxh = (u16*)d_ws;
    float *wxf, *wsum, *abp4;
    u16* cwh;
    if (use_partials) {
        wxf  = wsf;                        // unused in this path
        wsum = wsf + 2097152;              // 1024 f32
        abp4 = wsf + 2098176;              // 128 f32
        cwh  = (u16*)(wsf + 2098304);      // 8192 u16
        (void)hipMemsetAsync(wsum, 0, 1024 * sizeof(float), stream);
    } else {
        wxf  = wsf;                        // 262144 f32
        wsum = wsf + 262144;               // 1024 f32
        abp4 = wsf + 263168;               // 128 f32
        cwh  = (u16*)(wsf + 263296);       // 8192 u16
        (void)hipMemsetAsync(d_ws, 0, 263168 * sizeof(float), stream);
    }

    hipLaunchKernelGGL(enc_prep, dim3(1),   dim3(256), 0, stream, cw, scale, abp4, cwh);
    hipLaunchKernelGGL(enc_main, dim3(512), dim3(256), 0, stream, x, cwh, abp4, wxh, wxf, wsum, use_partials);
    if (use_partials)
        hipLaunchKernelGGL(enc_final_part,   dim3(1024), dim3(256), 0, stream, wxh, wsum, cw, out);
    else
        hipLaunchKernelGGL(enc_final_atomic, dim3(1024), dim3(256), 0, stream, wxf, wsum, cw, out);
}

// Round 17
// 39.372 us; speedup vs baseline: 1.4695x; 1.1493x over previous
//
#include <hip/hip_runtime.h>

// Encoding layer, fused, MFMA version. B=32, C=256, K=32, N=4096.
// R17 = R16 + prep folded into enc_main prologue (cw fragments + csq built inline
//       from fp32 cw under STAGE_LOAD(0) latency) + wsum via per-block stores
//       (no memset, no atomics). Graph: 2 dispatches (enc_main, enc_final).
// ws (partial path): wxh u16[512*8192] @0 | wsumP f32[512*32] @f32ofs 2097152
// ws (fallback):     wx f32[262144] @0 | wsumP f32[512*32] @262144

#define CC 256
#define KK 32
#define NN 4096
#define CN (CC*NN)
#define TOK 256
#define CHK 32
#define NCH 8

typedef unsigned int u32;
typedef unsigned short u16;
typedef __fp16 half2_t __attribute__((ext_vector_type(2)));
typedef _Float16 f16x8 __attribute__((ext_vector_type(8)));
typedef float f32x4 __attribute__((ext_vector_type(4)));
typedef u32 u32x2 __attribute__((ext_vector_type(2)));

__device__ __forceinline__ u32 pack2(float a, float b) {
    half2_t h = __builtin_amdgcn_cvt_pkrtz(a, b);
    u32 u;
    __builtin_memcpy(&u, &h, 4);
    return u;
}

__device__ __forceinline__ void bar_lgkm() {
    asm volatile("s_waitcnt lgkmcnt(0)" ::: "memory");
    __builtin_amdgcn_s_barrier();
    __builtin_amdgcn_sched_barrier(0);
}

#define STAGE_LOAD(CT) {                                                     \
    const float* xp = x + (size_t)b * CN + n0 + (CT) * CHK + (l & 7) * 4;    \
    _Pragma("unroll")                                                        \
    for (int it = 0; it < 8; ++it) {                                         \
        int ch = it * 32 + w * 8 + (l >> 3);                                 \
        sf[it] = *(const float4*)(xp + (size_t)ch * NN);                     \
    }                                                                        \
}
#define STAGE_WRITE(XTB, SQB) {                                              \
    float s0 = 0.f, s1 = 0.f, s2 = 0.f, s3 = 0.f;                            \
    int tq = l & 7;                                                          \
    _Pragma("unroll")                                                        \
    for (int it = 0; it < 8; ++it) {                                         \
        int ch = it * 32 + w * 8 + (l >> 3);                                 \
        float4 f = sf[it];                                                   \
        s0 += f.x * f.x; s1 += f.y * f.y;                                    \
        s2 += f.z * f.z; s3 += f.w * f.w;                                    \
        u32 u0 = pack2(f.x, f.y), u1 = pack2(f.z, f.w);                      \
        *(uint2*)(&(XTB)[((ch >> 2) * 2 + (tq >> 2)) * 64 +                  \
                         (ch & 3) * 16 + (tq & 3) * 4]) =                    \
            make_uint2(u0, u1);                                              \
    }                                                                        \
    s0 += __shfl_xor(s0, 8); s0 += __shfl_xor(s0, 16); s0 += __shfl_xor(s0, 32); \
    s1 += __shfl_xor(s1, 8); s1 += __shfl_xor(s1, 16); s1 += __shfl_xor(s1, 32); \
    s2 += __shfl_xor(s2, 8); s2 += __shfl_xor(s2, 16); s2 += __shfl_xor(s2, 32); \
    s3 += __shfl_xor(s3, 8); s3 += __shfl_xor(s3, 16); s3 += __shfl_xor(s3, 32); \
    if (l < 8) *(float4*)&(SQB)[w * 32 + tq * 4] = make_float4(s0, s1, s2, s3);  \
}

#define PA_ISSUE(KS, P, A0, A1) {                                                \
    asm volatile("ds_read_b64_tr_b16 %0, %1 offset:%2"                           \
                 : "=v"(trA[P][0]) : "v"(A0), "i"((KS) * 2048));                 \
    asm volatile("ds_read_b64_tr_b16 %0, %1 offset:%2"                           \
                 : "=v"(trA[P][1]) : "v"(A0), "i"((KS) * 2048 + 256));           \
    asm volatile("ds_read_b64_tr_b16 %0, %1 offset:%2"                           \
                 : "=v"(trA[P][2]) : "v"(A1), "i"((KS) * 2048));                 \
    asm volatile("ds_read_b64_tr_b16 %0, %1 offset:%2"                           \
                 : "=v"(trA[P][3]) : "v"(A1), "i"((KS) * 2048 + 256));           \
}

// ---------------- fused main: 512 blocks x 256 threads, 256 tokens each ----------------
__global__ __launch_bounds__(256, 2) void enc_main(
    const float* __restrict__ x, const float* __restrict__ cw,
    const float* __restrict__ scale, u16* __restrict__ wxh, float* __restrict__ wxf,
    float* __restrict__ wsumP, int use_partials) {

    __shared__ u16   xt[2][8192];     // 2 x 16 KB, double buffer (chunk parity)
    __shared__ u16   w2sp[4][1024];   // per-wave-private P [k][t]
    __shared__ float swsq[2][128];    // xsq partials, double buffer

    const int tid = threadIdx.x;
    const int l   = tid & 63;
    const int w   = tid >> 6;
    const int b   = blockIdx.x >> 4;
    const int blk = blockIdx.x & 15;
    const int n0  = blk * TOK;
    const int lg  = (l >> 4) & 3;

    float4 sf[8];
    STAGE_LOAD(0);    // start x HBM reads first; prologue below hides under them

    // ---- inline prep: cw A-frags + csq from fp32 cw (L2-hot, 32 KB) ----
    // lane's fragment k = Mt*16 + (l&15); ch = ks*32 + lg*8 .. +7
    uint4 cwA[8][2];
    float csqp[2] = {0.f, 0.f};
    #pragma unroll
    for (int Mt = 0; Mt < 2; ++Mt) {
        const float* cwp = cw + (size_t)(Mt * 16 + (l & 15)) * 256 + lg * 8;
        #pragma unroll
        for (int ks = 0; ks < 8; ++ks) {
            float4 f0 = *(const float4*)(cwp + ks * 32);
            float4 f1 = *(const float4*)(cwp + ks * 32 + 4);
            csqp[Mt] += f0.x * f0.x + f0.y * f0.y + f0.z * f0.z + f0.w * f0.w
                      + f1.x * f1.x + f1.y * f1.y + f1.z * f1.z + f1.w * f1.w;
            cwA[ks][Mt] = make_uint4(pack2(f0.x, f0.y), pack2(f0.z, f0.w),
                                     pack2(f1.x, f1.y), pack2(f1.z, f1.w));
        }
        // lg-groups tile all 256 ch: combine lanes l, l^16, l^32, l^48
        csqp[Mt] += __shfl_xor(csqp[Mt], 16);
        csqp[Mt] += __shfl_xor(csqp[Mt], 32);
    }
    // softmax per-k constants: lane's k = Mt*16 + lg*4 + r
    float Ak[2][4], Bk[2][4], Pk[2][4];
    #pragma unroll
    for (int Mt = 0; Mt < 2; ++Mt)
        #pragma unroll
        for (int r = 0; r < 4; ++r) {
            float A = scale[Mt * 16 + lg * 4 + r];
            float csqv = __shfl(csqp[Mt], lg * 4 + r);  // csq[Mt*16+j] lives in lane j (0-15)
            Ak[Mt][r] = A;
            Bk[Mt][r] = A * csqv;
            Pk[Mt][r] = -2.f * A;
        }

    f32x4 accb[4][2];   // [ch-tile q][k-tile nk]
    #pragma unroll
    for (int q = 0; q < 4; ++q)
        #pragma unroll
        for (int nk = 0; nk < 2; ++nk)
            accb[q][nk] = (f32x4){0.f, 0.f, 0.f, 0.f};
    float wsacc[2][4];
    #pragma unroll
    for (int Mt = 0; Mt < 2; ++Mt)
        #pragma unroll
        for (int r = 0; r < 4; ++r) wsacc[Mt][r] = 0.f;

    for (int ct = 0; ct < NCH; ++ct) {
        const int p2 = ct & 1;
        u16* xtb = &xt[p2][0];
        float* sqb = &swsq[p2][0];

        STAGE_WRITE(xtb, sqb);
        bar_lgkm();               // the ONLY barrier per chunk

        // ---- issue next-chunk global loads EARLY ----
        if (ct < NCH - 1) STAGE_LOAD(ct + 1);

        const u32 a0 = (u32)(uintptr_t)xtb + (4 * (l >> 4)) * 128 + (l & 15) * 8;
        const u32 a1 = a0 + 128;

        // ---- pass A: S[k][t] = Cw·X^T (cw frags in regs, tr_reads 1-deep) ----
        f32x4 acca[2][2];
        #pragma unroll
        for (int Mt = 0; Mt < 2; ++Mt)
            #pragma unroll
            for (int Nt = 0; Nt < 2; ++Nt)
                acca[Mt][Nt] = (f32x4){0.f, 0.f, 0.f, 0.f};
        {
            u32x2 trA[2][4];
            PA_ISSUE(0, 0, a0, a1);
            #pragma unroll
            for (int ks = 0; ks < 8; ++ks) {
                const int p = ks & 1;
                if (ks < 7) {
                    if (p == 0) { PA_ISSUE(ks + 1, 1, a0, a1); }
                    else        { PA_ISSUE(ks + 1, 0, a0, a1); }
                    asm volatile("s_waitcnt lgkmcnt(4)");
                } else {
                    asm volatile("s_waitcnt lgkmcnt(0)");
                }
                __builtin_amdgcn_sched_barrier(0);
                #pragma unroll
                for (int Nt = 0; Nt < 2; ++Nt) {
                    union { uint4 u; f16x8 h; } af;
                    af.u = make_uint4(trA[p][2 * Nt].x, trA[p][2 * Nt].y,
                                      trA[p][2 * Nt + 1].x, trA[p][2 * Nt + 1].y);
                    #pragma unroll
                    for (int Mt = 0; Mt < 2; ++Mt) {
                        union { uint4 u; f16x8 h; } cf;
                        cf.u = cwA[ks][Mt];
                        acca[Mt][Nt] = __builtin_amdgcn_mfma_f32_16x16x32_f16(
                            cf.h, af.h, acca[Mt][Nt], 0, 0, 0);
                    }
                }
            }
        }

        // ---- in-register softmax (token t = Nt*16 + (l&15)) ----
        {
            #pragma unroll
            for (int Nt = 0; Nt < 2; ++Nt) {
                int t = Nt * 16 + (l & 15);
                float xq = sqb[t] + sqb[32 + t] + sqb[64 + t] + sqb[96 + t];
                float lgt[2][4];
                float m = -3.4e38f;
                #pragma unroll
                for (int Mt = 0; Mt < 2; ++Mt)
                    #pragma unroll
                    for (int r = 0; r < 4; ++r) {
                        lgt[Mt][r] = fmaf(Ak[Mt][r], xq, Bk[Mt][r]) + Pk[Mt][r] * acca[Mt][Nt][r];
                        m = fmaxf(m, lgt[Mt][r]);
                    }
                m = fmaxf(m, __shfl_xor(m, 16));
                m = fmaxf(m, __shfl_xor(m, 32));
                float s = 0.f, e[2][4];
                #pragma unroll
                for (int Mt = 0; Mt < 2; ++Mt)
                    #pragma unroll
                    for (int r = 0; r < 4; ++r) { e[Mt][r] = __expf(lgt[Mt][r] - m); s += e[Mt][r]; }
                s += __shfl_xor(s, 16);
                s += __shfl_xor(s, 32);
                float rcp = 1.0f / s;
                #pragma unroll
                for (int Mt = 0; Mt < 2; ++Mt)
                    #pragma unroll
                    for (int r = 0; r < 4; ++r) {
                        float wv = e[Mt][r] * rcp;
                        wsacc[Mt][r] += wv;
                        union { __fp16 h; u16 u; } cv;
                        cv.h = (__fp16)wv;
                        w2sp[w][(Mt * 16 + lg * 4 + r) * 32 + Nt * 16 + (l & 15)] = cv.u;
                    }
            }
        }
        // w2sp same-wave write->read ordered by compiler-inserted lgkmcnt

        // ---- pass B: wx^T[ch][k] += X^T·P^T ----
        {
            f16x8 pB[2];
            #pragma unroll
            for (int nk = 0; nk < 2; ++nk)
                pB[nk] = *(const f16x8*)&w2sp[w][(nk * 16 + (l & 15)) * 32 + lg * 8];
            #pragma unroll
            for (int q = 0; q < 4; ++q) {
                int ch = (w * 4 + q) * 16 + (l & 15);
                const f16x8 xA = *(const f16x8*)&xtb[((ch >> 2) * 2 + (l >> 5)) * 64 +
                                                     (ch & 3) * 16 + ((l >> 4) & 1) * 8];
                #pragma unroll
                for (int nk = 0; nk < 2; ++nk)
                    accb[q][nk] = __builtin_amdgcn_mfma_f32_16x16x32_f16(xA, pB[nk], accb[q][nk], 0, 0, 0);
            }
        }
        // no trailing barrier: next STAGE_WRITE targets the other buffer
    }

    // ---- epilogue: wsum per-block plain stores (no atomics, no memset) ----
    #pragma unroll
    for (int Mt = 0; Mt < 2; ++Mt)
        #pragma unroll
        for (int r = 0; r < 4; ++r) {
            float v = wsacc[Mt][r];
            v += __shfl_xor(v, 1); v += __shfl_xor(v, 2);
            v += __shfl_xor(v, 4); v += __shfl_xor(v, 8);
            if (w == 0 && (l & 15) == 0)
                wsumP[blockIdx.x * KK + Mt * 16 + lg * 4 + r] = v;
        }
    // ---- wx^T partial stores: fp16 tile [ch][k] per block ----
    if (use_partials) {
        u16* dst = wxh + (size_t)blockIdx.x * 8192;
        #pragma unroll
        for (int q = 0; q < 4; ++q)
            #pragma unroll
            for (int nk = 0; nk < 2; ++nk)
                #pragma unroll
                for (int r = 0; r < 4; ++r) {
                    int ch = (w * 4 + q) * 16 + lg * 4 + r;
                    int k  = nk * 16 + (l & 15);
                    union { __fp16 h; u16 u; } cv;
                    cv.h = (__fp16)accb[q][nk][r];
                    dst[ch * 32 + k] = cv.u;
                }
    } else {
        #pragma unroll
        for (int q = 0; q < 4; ++q)
            #pragma unroll
            for (int nk = 0; nk < 2; ++nk)
                #pragma unroll
                for (int r = 0; r < 4; ++r) {
                    int ch = (w * 4 + q) * 16 + lg * 4 + r;
                    int k  = nk * 16 + (l & 15);
                    atomicAdd(&wxf[(size_t)b * 8192 + k * 256 + ch], accb[q][nk][r]);
                }
    }
}

// ---------------- finalize (partial path): fp16 tiles + wsumP reduce ----------------
__global__ void enc_final_part(const u16* __restrict__ wxh, const float* __restrict__ wsumP,
                               const float* __restrict__ cw, float* __restrict__ out) {
    int i = blockIdx.x * 256 + threadIdx.x;
    int k = i & 31, c = (i >> 5) & 255, b = i >> 13;
    const u16* p = wxh + (size_t)b * 16 * 8192 + c * 32 + k;
    float s = 0.f;
    #pragma unroll
    for (int j = 0; j < 16; ++j) {
        union { u16 u; __fp16 h; } cv;
        cv.u = p[(size_t)j * 8192];
        s += (float)cv.h;
    }
    float ws = 0.f;
    #pragma unroll
    for (int j = 0; j < 16; ++j)
        ws += wsumP[(b * 16 + j) * 32 + k];      // L2-broadcast, 64 KB total
    out[(size_t)b * 8192 + k * 256 + c] = s - ws * cw[k * 256 + c];
}

// ---------------- finalize (atomic fallback) ----------------
__global__ void enc_final_atomic(const float* __restrict__ wx, const float* __restrict__ wsumP,
                                 const float* __restrict__ cw, float* __restrict__ out) {
    int i = blockIdx.x * 256 + threadIdx.x;
    int c = i & 255, k = (i >> 8) & 31, b = i >> 13;
    float ws = 0.f;
    #pragma unroll
    for (int j = 0; j < 16; ++j)
        ws += wsumP[(b * 16 + j) * 32 + k];
    out[i] = wx[i] - ws * cw[k * 256 + c];
}

extern "C" void kernel_launch(void* const* d_in, const int* in_sizes, int n_in,
                              void* d_out, int out_size, void* d_ws, size_t ws_size,
                              hipStream_t stream) {
    (void)in_sizes; (void)n_in; (void)out_size;
    const float* x     = (const float*)d_in[0];
    const float* cw    = (const float*)d_in[1];
    const float* scale = (const float*)d_in[2];
    float* out = (float*)d_out;
    float* wsf = (float*)d_ws;

    // partial path: u16[512*8192] (=2097152 f32 slots) + wsumP f32[512*32]
    const size_t need = (size_t)(2097152 + 16384) * 4;
    const int use_partials = (ws_size >= need) ? 1 : 0;

    u16* wxh = (u16*)d_ws;
    float *wxf, *wsumP;
    if (use_partials) {
        wxf   = wsf;                       // unused in this path
        wsumP = wsf + 2097152;             // 16384 f32
    } else {
        wxf   = wsf;                       // 262144 f32
        wsumP = wsf + 262144;              // 16384 f32
        (void)hipMemsetAsync(d_ws, 0, 262144 * sizeof(float), stream);
    }

    hipLaunchKernelGGL(enc_main, dim3(512), dim3(256), 0, stream,
                       x, cw, scale, wxh, wxf, wsumP, use_partials);
    if (use_partials)
        hipLaunchKernelGGL(enc_final_part,   dim3(1024), dim3(256), 0, stream, wxh, wsumP, cw, out);
    else
        hipLaunchKernelGGL(enc_final_atomic, dim3(1024), dim3(256), 0, stream, wxf, wsumP, cw, out);
}